// Round 5
// baseline (124.697 us; speedup 1.0000x reference)
//
#include <hip/hip_runtime.h>
#include <stdint.h>

typedef short bf16x8 __attribute__((ext_vector_type(8)));
typedef unsigned short u16x8 __attribute__((ext_vector_type(8)));
typedef float f32x4 __attribute__((ext_vector_type(4)));
typedef float f32x8 __attribute__((ext_vector_type(8)));

constexpr int BT_TOT = 768;   // B*T
constexpr int M_N    = 512;   // nodes (contraction length for stage 1)
constexpr int DD     = 64;    // Din = Dout
constexpr int WROW   = 72;    // W' row stride in route_mm (144B, bank step 4)

__device__ __forceinline__ unsigned short f2bf(float f) {
  unsigned u = __builtin_bit_cast(unsigned, f);
  u += 0x7fffu + ((u >> 16) & 1u);          // RNE
  return (unsigned short)(u >> 16);
}

// ---------------- prep: adj f32 -> bf16 (once) ----------------
__global__ __launch_bounds__(256)
void prep_adj(const float* __restrict__ adjg, unsigned short* __restrict__ wsadj) {
  int i = (blockIdx.x * 256 + threadIdx.x) * 8;
  f32x8 a = *(const f32x8*)(adjg + i);
  u16x8 r;
  #pragma unroll
  for (int j = 0; j < 8; ++j) r[j] = f2bf(a[j]);
  *(u16x8*)(wsadj + i) = r;
}

// ---------------- Kernel A ----------------
// H[bt][m][d] = sum_n adj[m][n] * x[bt][n][d]  (bf16), one WG per bt, all 512 m.
// 8 waves; wave wv owns m in [wv*64, wv*64+64). x staged in 4 double-buffered
// 128-n chunks (16 KB each) so chunk c+1's HBM loads overlap chunk c's MFMA.
// H lands in the FIRST 128B of each 256B d_out row; route_mm overwrites rows.
template<bool WS>
__global__ __launch_bounds__(512, 4)
void gconv_h(const float* __restrict__ xg,             // [768][512][64] f32
             const float* __restrict__ adjf,           // [512][512] f32 (fallback)
             const unsigned short* __restrict__ adjb,  // [512][512] bf16 (ws path)
             char* __restrict__ hout)
{
  __shared__ unsigned short xTc[2][64 * 128];   // 2 x 16 KB -> 2 WG/CU with 512 thr

  const int bt   = blockIdx.x;
  const int tid  = threadIdx.x;
  const int lane = tid & 63;
  const int wv   = tid >> 6;        // wave 0..7: owns m in [wv*64, wv*64+64)
  const int l15  = lane & 15;
  const int gg   = lane >> 4;       // k-group 0..3
  const int nd   = tid & 63;        // n-pair index for staging (n = nd*2)
  const int dct  = tid >> 6;        // d-oct for staging

  const float* xb = xg + (size_t)bt * (M_N * DD);

  // prologue: load chunk 0 (2 x f32x8 per thread)
  f32x8 x0, x1;
  { const float* p = xb + (nd*2)*DD + dct*8;
    x0 = *(const f32x8*)p;  x1 = *(const f32x8*)(p + DD); }

  f32x4 acc[4][4];
  #pragma unroll
  for (int mt = 0; mt < 4; ++mt)
    #pragma unroll
    for (int dt = 0; dt < 4; ++dt) acc[mt][dt] = f32x4{0.f,0.f,0.f,0.f};

  #pragma unroll
  for (int c = 0; c < 4; ++c) {
    unsigned short* xt = &xTc[c & 1][0];
    // transpose-pack chunk c: xt[d][n] = bf16(x[bt][c*128+n][d]), XOR-swizzled:
    // elem(d, n) at d*128 + ((n/8) ^ (d&7))*8 + n%8
    #pragma unroll
    for (int e = 0; e < 8; ++e) {
      int d = dct*8 + e;
      unsigned v = (unsigned)f2bf(x0[e]) | ((unsigned)f2bf(x1[e]) << 16);
      *(unsigned*)(xt + d*128 + (((nd>>2) ^ e) * 8) + (nd&3)*2) = v;  // b32, 2-way
    }
    if (c < 3) {  // prefetch chunk c+1: stays in flight during chunk-c MFMA
      const float* p = xb + ((c+1)*128 + nd*2)*DD + dct*8;
      x0 = *(const f32x8*)p;  x1 = *(const f32x8*)(p + DD);
    }
    __syncthreads();   // one barrier per chunk (alternating buffers -> race-free)

    #pragma unroll
    for (int kl = 0; kl < 4; ++kl) {
      const int kg = c*4 + kl;                 // global k-slice (32 n each)
      bf16x8 afr[4];
      #pragma unroll
      for (int mt = 0; mt < 4; ++mt) {
        const int m = wv*64 + mt*16 + l15;
        if (WS) {
          afr[mt] = __builtin_bit_cast(bf16x8,
              *(const u16x8*)(adjb + (size_t)m*M_N + kg*32 + gg*8));
        } else {
          f32x8 a = *(const f32x8*)(adjf + (size_t)m*M_N + kg*32 + gg*8);
          u16x8 r;
          #pragma unroll
          for (int j = 0; j < 8; ++j) r[j] = f2bf(a[j]);
          afr[mt] = __builtin_bit_cast(bf16x8, r);
        }
      }
      #pragma unroll
      for (int dt = 0; dt < 4; ++dt) {
        const int d = dt*16 + l15;
        bf16x8 bfx = __builtin_bit_cast(bf16x8,
            *(const u16x8*)(xt + d*128 + (((kl*4 + gg) ^ (l15 & 7)))*8));
        #pragma unroll
        for (int mt = 0; mt < 4; ++mt)
          acc[mt][dt] = __builtin_amdgcn_mfma_f32_16x16x32_bf16(afr[mt], bfx,
                                                                acc[mt][dt], 0,0,0);
      }
    }
  }

  // epilogue: H store (bf16, low half of each d_out row)
  #pragma unroll
  for (int mt = 0; mt < 4; ++mt)
    #pragma unroll
    for (int dt = 0; dt < 4; ++dt)
      #pragma unroll
      for (int r = 0; r < 4; ++r) {
        int m = wv*64 + mt*16 + gg*4 + r;      // C row = (lane>>4)*4 + reg
        int d = dt*16 + l15;
        *(unsigned short*)(hout + ((size_t)bt*M_N + m)*256 + 2*d)
            = f2bf(acc[mt][dt][r]);
      }
}

// ---------------- Kernel B (unchanged, verified; ~7 us) ----------------
__global__ __launch_bounds__(256, 4)
void route_mm(const char* __restrict__ hin,
              const float* __restrict__ wgt,
              const float* __restrict__ bias,
              float* __restrict__ outg)
{
  __shared__ unsigned short wb[128 * WROW];

  const int m0    = blockIdx.x * 2;
  const int btblk = blockIdx.y * 64;
  const int tid   = threadIdx.x;
  const int lane  = tid & 63;
  const int wv    = tid >> 6;
  const int l15   = lane & 15;
  const int gg    = lane >> 4;
  const int dp    = tid & 31;
  const int lo    = tid >> 5;

  { const float* q = wgt + ((size_t)m0*64 + dp*2)*64 + lo*8;
    f32x8 w0 = *(const f32x8*)q;          f32x8 w1 = *(const f32x8*)(q+64);
    f32x8 w2 = *(const f32x8*)(q+4096);   f32x8 w3 = *(const f32x8*)(q+4160);
    #pragma unroll
    for (int e = 0; e < 8; ++e) {
      int lrow = lo*8 + e;
      unsigned v0 = (unsigned)f2bf(w0[e]) | ((unsigned)f2bf(w1[e]) << 16);
      unsigned v1 = (unsigned)f2bf(w2[e]) | ((unsigned)f2bf(w3[e]) << 16);
      *(unsigned*)(wb + lrow*WROW + dp*2)        = v0;
      *(unsigned*)(wb + (64 + lrow)*WROW + dp*2) = v1;
    }
  }
  __syncthreads();

  const int btw0 = btblk + wv*16;

  #pragma unroll
  for (int mm = 0; mm < 2; ++mm) {
    const int m = m0 + mm;
    bf16x8 afr[2];
    #pragma unroll
    for (int ks = 0; ks < 2; ++ks) {
      const char* hp = hin + ((size_t)(btw0 + l15)*M_N + m)*256 + ks*64 + gg*16;
      afr[ks] = __builtin_bit_cast(bf16x8, *(const u16x8*)hp);
    }
    f32x4 acc[4];
    #pragma unroll
    for (int lt = 0; lt < 4; ++lt) acc[lt] = f32x4{0.f,0.f,0.f,0.f};
    #pragma unroll
    for (int lt = 0; lt < 4; ++lt)
      #pragma unroll
      for (int ks = 0; ks < 2; ++ks) {
        bf16x8 bfr = __builtin_bit_cast(bf16x8,
            *(const u16x8*)(wb + (mm*64 + lt*16 + l15)*WROW + ks*32 + gg*8));
        acc[lt] = __builtin_amdgcn_mfma_f32_16x16x32_bf16(afr[ks], bfr, acc[lt], 0,0,0);
      }
    #pragma unroll
    for (int lt = 0; lt < 4; ++lt) {
      float bv = bias[m*64 + lt*16 + l15];
      #pragma unroll
      for (int r = 0; r < 4; ++r) {
        size_t row = (size_t)(btw0 + gg*4 + r)*M_N + m;
        outg[row*64 + lt*16 + l15] = acc[lt][r] + bv;
      }
    }
  }
}

extern "C" void kernel_launch(void* const* d_in, const int* in_sizes, int n_in,
                              void* d_out, int out_size, void* d_ws, size_t ws_size,
                              hipStream_t stream) {
  const float* xg   = (const float*)d_in[0];
  const float* adjg = (const float*)d_in[1];
  const float* wgt  = (const float*)d_in[2];
  const float* bg   = (const float*)d_in[3];

  const size_t adj_bf_bytes = (size_t)M_N * M_N * 2;   // 512 KB
  if (ws_size >= adj_bf_bytes) {
    unsigned short* wsadj = (unsigned short*)d_ws;
    prep_adj<<<dim3(M_N * M_N / (256 * 8)), dim3(256), 0, stream>>>(adjg, wsadj);
    gconv_h<true><<<dim3(BT_TOT), dim3(512), 0, stream>>>(
        xg, adjg, wsadj, (char*)d_out);
  } else {
    gconv_h<false><<<dim3(BT_TOT), dim3(512), 0, stream>>>(
        xg, adjg, nullptr, (char*)d_out);
  }
  route_mm<<<dim3(M_N/2, BT_TOT/64), dim3(256), 0, stream>>>(
      (const char*)d_out, wgt, bg, (float*)d_out);
}